// Round 1
// baseline (256.021 us; speedup 1.0000x reference)
//
#include <hip/hip_runtime.h>

// Problem dims (fixed by setup_inputs)
constexpr int Bc = 4, Cc = 128, Hc = 192, Wc = 192;
constexpr int HI = 96, WI = 96;       // half-res inputs
constexpr int NB = 64;                // n_bins
constexpr int NA = 16;                // n_att
constexpr float SCL = 95.0f / 191.0f; // align_corners scale (96->192)

typedef __attribute__((ext_vector_type(8))) short bf16x8;
typedef __attribute__((ext_vector_type(4))) float f32x4;

__device__ __forceinline__ unsigned short f2bf(float f) {
  unsigned u = __builtin_bit_cast(unsigned, f);
  unsigned r = (u + 0x7FFFu + ((u >> 16) & 1u)) >> 16;   // RNE
  return (unsigned short)r;
}
__device__ __forceinline__ float rcp_fast(float r) {
#if defined(__has_builtin)
#if __has_builtin(__builtin_amdgcn_rcpf)
  return __builtin_amdgcn_rcpf(r);
#else
  return 1.0f / r;
#endif
#else
  return 1.0f / r;
#endif
}

// ---------------------------------------------------------------------------
// Prep: w1 (128x128 f32) -> bf16; even rows of w2 (16x128) -> bf16. Into ws.
// ---------------------------------------------------------------------------
__global__ __launch_bounds__(256) void k_prep(
    const float* __restrict__ w1, const float* __restrict__ w2,
    unsigned short* __restrict__ w1bf, unsigned short* __restrict__ w2bf)
{
  const int t = blockIdx.x * 256 + threadIdx.x;   // 0..18431
  if (t < 16384) {
    w1bf[t] = f2bf(w1[t]);
  } else {
    const int u = t - 16384;                      // 0..2047
    const int j = u >> 7, c = u & 127;
    w2bf[u] = f2bf(w2[(2 * j) * 128 + c]);        // even rows only
  }
}

// ---------------------------------------------------------------------------
// K1 (MFMA): h = x + bilinear(pbe); a1 = relu(h@w1^T+b1);
//            att = relu(a1@w2e^T+b2e)+1e-3  -> att_ws[b][y][x][j]
// One block per (b, y, 64-px x-tile). 256 threads = 4 waves.
// x loads hoisted ABOVE phase 1 so both global-load batches share one
// latency round. Row cache is f32 pitch-37 (odd -> qd groups bank-spread;
// af build = 32 ds_read2_b32 per lane instead of 128 ds_read_u16).
// LDS 18944 B; a1_s[64][136]bf16 (17408 B) aliases row_s after the barrier.
//
// R1: __launch_bounds__(256,4) -> (256,8). Counters showed latency-bound
// (MfmaUtil 2.8%, VALUBusy 18%, HBM 20%, Occ 36%); resources allow 8
// blocks/CU (LDS 8x18944=151.5KB<=160KB, VGPR 56<=64). Double the waves.
// ---------------------------------------------------------------------------
__global__ __launch_bounds__(256, 8) void k_att(
    const float* __restrict__ x, const float* __restrict__ pbe,
    const unsigned short* __restrict__ w1bf, const float* __restrict__ b1,
    const unsigned short* __restrict__ w2bf, const float* __restrict__ b2,
    float* __restrict__ att)
{
  constexpr int PH = 136;   // a1_s pitch (bf16)
  constexpr int RP = 37;    // row_s pitch (f32), odd
  __shared__ __align__(16) unsigned char smem[128 * RP * 4];    // 18944 B
  float*          row_s = (float*)smem;                         // [128][37]
  unsigned short* a1_s  = (unsigned short*)smem;                // [64][136]

  const int tid = threadIdx.x;
  const int xg0 = blockIdx.x * 64;
  const int y = blockIdx.y;
  const int b = blockIdx.z;

  const float ysf = y * SCL;
  const int y0 = (int)ysf;
  const int y1 = min(y0 + 1, HI - 1);
  const float wy = ysf - (float)y0;
  const int xi0 = (int)(xg0 * SCL);

  const int lane = tid & 63;
  const int wv = tid >> 6;        // wave id 0..3
  const int ln = lane & 15;
  const int qd = lane >> 4;
  const int m0 = wv * 16;

  const int px = m0 + ln;
  const int xg = xg0 + px;
  const float xsf = (float)xg * SCL;
  const int x0i = (int)xsf;
  const float wx = xsf - (float)x0i;
  const int xl = x0i - xi0;             // 0..32, xl+1 <= 33

  // ---- hoisted x loads: xr[kt*8+j] = x[c = kt*32+qd*8+j][y][xg]
  float xr[32];
  #pragma unroll
  for (int kt = 0; kt < 4; ++kt) {
    #pragma unroll
    for (int j = 0; j < 8; ++j) {
      const int c = kt * 32 + qd * 8 + j;
      xr[kt * 8 + j] = x[((size_t)(b * Cc + c) * Hc + y) * Wc + xg];
    }
  }

  // ---- phase 1: row_s[c][xi] = y-interp of pbe (coalesced loads, f32)
  #pragma unroll
  for (int i = 0; i < 18; ++i) {
    const int f = tid + 256 * i;        // 0..4607
    const int c = f / 36;
    const int xi = f - c * 36;
    const int xgl = min(xi0 + xi, WI - 1);
    const float* p = pbe + (size_t)(b * Cc + c) * (HI * WI);
    const float top = p[y0 * WI + xgl];
    const float bot = p[y1 * WI + xgl];
    row_s[c * RP + xi] = top + wy * (bot - top);
  }
  __syncthreads();

  // ---- build A-fragments in registers from xr + row_s
  bf16x8 af[4];
  #pragma unroll
  for (int kt = 0; kt < 4; ++kt) {
    #pragma unroll
    for (int j = 0; j < 8; ++j) {
      const int c = kt * 32 + qd * 8 + j;
      const float v0 = row_s[c * RP + xl];
      const float v1 = row_s[c * RP + xl + 1];
      af[kt][j] = (short)f2bf(xr[kt * 8 + j] + v0 + wx * (v1 - v0));
    }
  }
  __syncthreads();   // row_s dead -> region reusable as a1_s

  // ---- GEMM1: C[64m][128n] = h[64m][128k] * w1[128n][128k]^T (B from global)
  f32x4 acc[8];
  #pragma unroll
  for (int nt = 0; nt < 8; ++nt) acc[nt] = f32x4{0.f, 0.f, 0.f, 0.f};
  #pragma unroll
  for (int nt = 0; nt < 8; ++nt) {
    #pragma unroll
    for (int kt = 0; kt < 4; ++kt) {
      const bf16x8 bf = *(const bf16x8*)&w1bf[(nt * 16 + ln) * 128 + kt * 32 + qd * 8];
      acc[nt] = __builtin_amdgcn_mfma_f32_16x16x32_bf16(af[kt], bf, acc[nt], 0, 0, 0);
    }
  }

  // epilogue: relu(+bias) -> a1_s (bf16). Wave writes only its own 16 rows.
  #pragma unroll
  for (int nt = 0; nt < 8; ++nt) {
    const int n = nt * 16 + ln;
    const float bias = b1[n];
    #pragma unroll
    for (int r = 0; r < 4; ++r) {
      const int m = m0 + qd * 4 + r;
      a1_s[m * PH + n] = f2bf(fmaxf(acc[nt][r] + bias, 0.f));
    }
  }
  // no __syncthreads: each wave reads back only rows it wrote (DS in-order/wave)

  // ---- GEMM2: att[64m][16j] = a1[64m][128k] * w2e[16j][128k]^T
  f32x4 acc2 = f32x4{0.f, 0.f, 0.f, 0.f};
  #pragma unroll
  for (int kt = 0; kt < 4; ++kt) {
    const bf16x8 a2 = *(const bf16x8*)&a1_s[(m0 + ln) * PH + kt * 32 + qd * 8];
    const bf16x8 b2f = *(const bf16x8*)&w2bf[ln * 128 + kt * 32 + qd * 8];
    acc2 = __builtin_amdgcn_mfma_f32_16x16x32_bf16(a2, b2f, acc2, 0, 0, 0);
  }
  const float bias2 = b2[2 * ln];
  #pragma unroll
  for (int r = 0; r < 4; ++r) {
    const int opx = m0 + qd * 4 + r;
    const float v = fmaxf(acc2[r] + bias2, 0.f) + 0.001f;
    att[((size_t)((b * Hc + y) * Wc) + xg0 + opx) * NA + ln] = v;
  }
}

// ---------------------------------------------------------------------------
// K2: block = one image row (192 threads), thread = pixel.
// pb y-interpolated at stage time -> row_s[64][96] f32 (24 KB -> 6 blk/CU),
// delta with 4 bins in flight, register bitonic sort.
// ---------------------------------------------------------------------------
__global__ __launch_bounds__(192, 2) void k_bins(
    const float* __restrict__ pb, const float* __restrict__ att,
    float* __restrict__ out0, float* __restrict__ out1)
{
  __shared__ __align__(16) float row_s[NB][WI];   // 24576 B

  const int tid = threadIdx.x;      // = xg
  const int y = blockIdx.x;
  const int b = blockIdx.y;

  const float ysf = y * SCL;
  const int y0 = (int)ysf;
  const int y1 = min(y0 + 1, HI - 1);
  const float wy = ysf - (float)y0;

  // att for this pixel: 16 floats, contiguous — issue first (independent)
  float am[16];
  {
    const float4* ap = (const float4*)(att + ((size_t)((b * Hc + y) * Wc) + tid) * NA);
    const float4 a0 = ap[0], a1 = ap[1], a2 = ap[2], a3 = ap[3];
    am[0] = a0.x;  am[1] = a0.y;  am[2] = a0.z;  am[3] = a0.w;
    am[4] = a1.x;  am[5] = a1.y;  am[6] = a1.z;  am[7] = a1.w;
    am[8] = a2.x;  am[9] = a2.y;  am[10] = a2.z; am[11] = a2.w;
    am[12] = a3.x; am[13] = a3.y; am[14] = a3.z; am[15] = a3.w;
  }

  // ---- stage y-interpolated pb rows for all 64 bins: 1536 float4 positions
  #pragma unroll
  for (int i = 0; i < 8; ++i) {
    const int u = tid + 192 * i;          // 0..1535
    const int k = u / 24;
    const int g = u - k * 24;             // float4 group in row
    const float* base = pb + (size_t)(b * NB + k) * (HI * WI);
    const float4 t4 = *(const float4*)&base[y0 * WI + g * 4];
    const float4 b4 = *(const float4*)&base[y1 * WI + g * 4];
    float4 r;
    r.x = t4.x + wy * (b4.x - t4.x);
    r.y = t4.y + wy * (b4.y - t4.y);
    r.z = t4.z + wy * (b4.z - t4.z);
    r.w = t4.w + wy * (b4.w - t4.w);
    *(float4*)&row_s[k][g * 4] = r;
  }
  __syncthreads();

  const float xsf = tid * SCL;
  const int x0 = (int)xsf;          // <= 94
  const float wx = xsf - (float)x0;

  const size_t obase = (size_t)(b * NB) * (Hc * Wc) + (size_t)y * Wc + tid;
  float v[NB];

  // ---- delta: 4 bins in flight -> 4 independent rcp chains
  #pragma unroll
  for (int kb = 0; kb < NB; kb += 4) {
    float bc[4], dl[4];
    #pragma unroll
    for (int q = 0; q < 4; ++q) {
      const int k = kb + q;
      const float v0 = row_s[k][x0], v1 = row_s[k][x0 + 1];
      bc[q] = v0 + wx * (v1 - v0);
      dl[q] = 0.f;
    }
    #pragma unroll
    for (int j = 0; j < NA; ++j) {
      const float a = am[j];
      #pragma unroll
      for (int q = 0; q < 4; ++q) {
        const float d = a - bc[q];
        const float rq = fmaf(300.f * d, d, 1.f);
        dl[q] = fmaf(d, rcp_fast(rq), dl[q]);
      }
    }
    #pragma unroll
    for (int q = 0; q < 4; ++q) {
      const float bnc = fmaf(dl[q], 1.f / 16.f, bc[q]);
      out0[obase + (size_t)(kb + q) * (Hc * Wc)] = bnc;
      v[kb + q] = fmaf(9.999f, bnc, 0.001f);
    }
  }

  // ---- fully-unrolled bitonic sort on 64 registers (ascending)
  #pragma unroll
  for (int size = 2; size <= NB; size <<= 1) {
    #pragma unroll
    for (int stride = size >> 1; stride >= 1; stride >>= 1) {
      #pragma unroll
      for (int i = 0; i < NB; ++i) {
        if ((i & stride) == 0) {
          const int j = i | stride;
          const bool asc = ((i & size) == 0);
          const float a = v[i], c = v[j];
          const float lo = fminf(a, c), hi = fmaxf(a, c);
          v[i] = asc ? lo : hi;
          v[j] = asc ? hi : lo;
        }
      }
    }
  }

  #pragma unroll
  for (int k = 0; k < NB; ++k) {
    out1[obase + (size_t)k * (Hc * Wc)] = fminf(fmaxf(v[k], 0.001f), 10.0f);
  }
}

// ---------------------------------------------------------------------------
extern "C" void kernel_launch(void* const* d_in, const int* in_sizes, int n_in,
                              void* d_out, int out_size, void* d_ws, size_t ws_size,
                              hipStream_t stream) {
  const float* x   = (const float*)d_in[0];   // (4,128,192,192)
  const float* pb  = (const float*)d_in[1];   // (4,64,96,96)
  const float* pbe = (const float*)d_in[2];   // (4,128,96,96)
  const float* w1  = (const float*)d_in[3];   // (128,128)
  const float* b1  = (const float*)d_in[4];   // (128,)
  const float* w2  = (const float*)d_in[5];   // (32,128)
  const float* b2  = (const float*)d_in[6];   // (32,)

  float* out0 = (float*)d_out;                       // bin_new_centers
  float* out1 = out0 + (size_t)Bc * NB * Hc * Wc;    // bin_centers

  // ws layout: [w1bf 32KB][w2bf 4KB][pad to 64KB][att f32 9.4MB]
  unsigned short* w1bf = (unsigned short*)d_ws;
  unsigned short* w2bf = w1bf + 16384;
  float* att = (float*)((char*)d_ws + 65536);        // [b][y][x][j]

  k_prep<<<72, 256, 0, stream>>>(w1, w2, w1bf, w2bf);

  dim3 g1(Wc / 64, Hc, Bc);
  k_att<<<g1, 256, 0, stream>>>(x, pbe, w1bf, b1, w2bf, b2, att);

  dim3 g2(Hc, Bc);
  k_bins<<<g2, 192, 0, stream>>>(pb, att, out0, out1);
}

// Round 2
// 217.250 us; speedup vs baseline: 1.1785x; 1.1785x over previous
//
#include <hip/hip_runtime.h>

// Problem dims (fixed by setup_inputs)
constexpr int Bc = 4, Cc = 128, Hc = 192, Wc = 192;
constexpr int HI = 96, WI = 96;       // half-res inputs
constexpr int NB = 64;                // n_bins
constexpr int NA = 16;                // n_att
constexpr float SCL = 95.0f / 191.0f; // align_corners scale (96->192)

typedef __attribute__((ext_vector_type(8))) short bf16x8;
typedef __attribute__((ext_vector_type(4))) float f32x4;

__device__ __forceinline__ unsigned short f2bf(float f) {
  unsigned u = __builtin_bit_cast(unsigned, f);
  unsigned r = (u + 0x7FFFu + ((u >> 16) & 1u)) >> 16;   // RNE
  return (unsigned short)r;
}
__device__ __forceinline__ float rcp_fast(float r) {
#if defined(__has_builtin)
#if __has_builtin(__builtin_amdgcn_rcpf)
  return __builtin_amdgcn_rcpf(r);
#else
  return 1.0f / r;
#endif
#else
  return 1.0f / r;
#endif
}

// ---------------------------------------------------------------------------
// Prep: pack w1 / even rows of w2 into MFMA-fragment order (bf16):
//   w1p[(nt*4+kt)*512 + l*8 + e] = w1[(nt*16 + (l&15))*128 + kt*32 + (l>>4)*8 + e]
//   w2p[kt*512 + l*8 + e]        = w2[(2*(l&15))*128   + kt*32 + (l>>4)*8 + e]
// So in k_att, lane l's B-fragment for (nt,kt) is 16 contiguous bytes at
// lane-linear addresses -> LDS staging is conflict-free ds_read_b128.
// ---------------------------------------------------------------------------
__global__ __launch_bounds__(256) void k_prep(
    const float* __restrict__ w1, const float* __restrict__ w2,
    unsigned short* __restrict__ w1p, unsigned short* __restrict__ w2p)
{
  const int t = blockIdx.x * 256 + threadIdx.x;   // 0..18431
  if (t < 16384) {
    const int e  = t & 7;
    const int l  = (t >> 3) & 63;
    const int kt = (t >> 9) & 3;
    const int nt = t >> 11;
    const int n  = nt * 16 + (l & 15);
    const int k  = kt * 32 + (l >> 4) * 8 + e;
    w1p[t] = f2bf(w1[n * 128 + k]);
  } else {
    const int u  = t - 16384;                     // 0..2047
    const int e  = u & 7;
    const int l  = (u >> 3) & 63;
    const int kt = u >> 9;
    const int n  = 2 * (l & 15);                  // even rows only
    const int k  = kt * 32 + (l >> 4) * 8 + e;
    w2p[u] = f2bf(w2[n * 128 + k]);
  }
}

// ---------------------------------------------------------------------------
// K1 (MFMA): h = x + bilinear(pbe); a1 = relu(h@w1^T+b1);
//            att = relu(a1@w2e^T+b2e)+1e-3  -> att_ws[b][y][x][j]
// One block per (b, y, 64-px x-tile). 256 threads = 4 waves.
//
// R2: GEMM1's B-operand was read from global per-MFMA (32 x 16B L2 loads/lane,
// ~200cy each, few in flight at 56 VGPR) -> exposed ~2000cy/block chain and
// MfmaUtil 2.8%. Now w1 is pre-packed in fragment order and staged to LDS once
// per block (8 float4/thread, issued at kernel start so the copy shares the
// HBM latency round with x/pbe). GEMM1 B-reads become conflict-free
// ds_read_b128 at base+lane*16. LDS 32KB(w1_s)+18.9KB(row_s/a1_s)=51.7KB
// -> 3 blocks/CU; launch_bounds(256,3) gives ~170 VGPR for hoisting.
// R1 lesson: (256,8) crushed VGPRs to 32 and regressed 72->88us; reverted.
// ---------------------------------------------------------------------------
__global__ __launch_bounds__(256, 3) void k_att(
    const float* __restrict__ x, const float* __restrict__ pbe,
    const unsigned short* __restrict__ w1p, const float* __restrict__ b1,
    const unsigned short* __restrict__ w2p, const float* __restrict__ b2,
    float* __restrict__ att)
{
  constexpr int PH = 136;   // a1_s pitch (bf16)
  constexpr int RP = 37;    // row_s pitch (f32), odd
  // [w1_s 32768B][row_s(=a1_s alias) 18944B] = 51712 B total
  __shared__ __align__(16) unsigned char smem[32768 + 128 * RP * 4];
  unsigned short* w1_s  = (unsigned short*)smem;                // [4096*8] frag-linear
  float*          row_s = (float*)(smem + 32768);               // [128][37]
  unsigned short* a1_s  = (unsigned short*)(smem + 32768);      // [64][136]

  const int tid = threadIdx.x;
  const int xg0 = blockIdx.x * 64;
  const int y = blockIdx.y;
  const int b = blockIdx.z;

  const float ysf = y * SCL;
  const int y0 = (int)ysf;
  const int y1 = min(y0 + 1, HI - 1);
  const float wy = ysf - (float)y0;
  const int xi0 = (int)(xg0 * SCL);

  const int lane = tid & 63;
  const int wv = tid >> 6;        // wave id 0..3
  const int ln = lane & 15;
  const int qd = lane >> 4;
  const int m0 = wv * 16;

  const int px = m0 + ln;
  const int xg = xg0 + px;
  const float xsf = (float)xg * SCL;
  const int x0i = (int)xsf;
  const float wx = xsf - (float)x0i;
  const int xl = x0i - xi0;             // 0..32, xl+1 <= 33

  // ---- w1p stage loads (global->reg), issued first: 8 x float4 per thread
  float4 wstage[8];
  {
    const float4* wp4 = (const float4*)w1p;   // 2048 float4
    #pragma unroll
    for (int i = 0; i < 8; ++i) wstage[i] = wp4[tid + 256 * i];
  }

  // ---- hoisted w2 fragments (4 x 16B, L2-hot) + biases
  bf16x8 b2f[4];
  #pragma unroll
  for (int kt = 0; kt < 4; ++kt)
    b2f[kt] = *(const bf16x8*)&w2p[kt * 512 + lane * 8];
  float bias1[8];
  #pragma unroll
  for (int nt = 0; nt < 8; ++nt) bias1[nt] = b1[nt * 16 + ln];
  const float bias2 = b2[2 * ln];

  // ---- hoisted x loads: xr[kt*8+j] = x[c = kt*32+qd*8+j][y][xg]
  float xr[32];
  #pragma unroll
  for (int kt = 0; kt < 4; ++kt) {
    #pragma unroll
    for (int j = 0; j < 8; ++j) {
      const int c = kt * 32 + qd * 8 + j;
      xr[kt * 8 + j] = x[((size_t)(b * Cc + c) * Hc + y) * Wc + xg];
    }
  }

  // ---- phase 1: row_s[c][xi] = y-interp of pbe (coalesced loads, f32)
  #pragma unroll
  for (int i = 0; i < 18; ++i) {
    const int f = tid + 256 * i;        // 0..4607
    const int c = f / 36;
    const int xi = f - c * 36;
    const int xgl = min(xi0 + xi, WI - 1);
    const float* p = pbe + (size_t)(b * Cc + c) * (HI * WI);
    const float top = p[y0 * WI + xgl];
    const float bot = p[y1 * WI + xgl];
    row_s[c * RP + xi] = top + wy * (bot - top);
  }

  // ---- w1 stage: reg -> LDS (linear, conflict-free)
  {
    float4* ws4 = (float4*)w1_s;
    #pragma unroll
    for (int i = 0; i < 8; ++i) ws4[tid + 256 * i] = wstage[i];
  }
  __syncthreads();

  // ---- build A-fragments in registers from xr + row_s
  bf16x8 af[4];
  #pragma unroll
  for (int kt = 0; kt < 4; ++kt) {
    #pragma unroll
    for (int j = 0; j < 8; ++j) {
      const int c = kt * 32 + qd * 8 + j;
      const float v0 = row_s[c * RP + xl];
      const float v1 = row_s[c * RP + xl + 1];
      af[kt][j] = (short)f2bf(xr[kt * 8 + j] + v0 + wx * (v1 - v0));
    }
  }
  __syncthreads();   // row_s dead -> region reusable as a1_s

  // ---- GEMM1: C[64m][128n] = h[64m][128k] * w1[128n][128k]^T
  //      B from LDS, fragment-linear: ds_read_b128 at base + lane*16
  f32x4 acc[8];
  #pragma unroll
  for (int nt = 0; nt < 8; ++nt) acc[nt] = f32x4{0.f, 0.f, 0.f, 0.f};
  #pragma unroll
  for (int nt = 0; nt < 8; ++nt) {
    #pragma unroll
    for (int kt = 0; kt < 4; ++kt) {
      const bf16x8 bf = *(const bf16x8*)&w1_s[(nt * 4 + kt) * 512 + lane * 8];
      acc[nt] = __builtin_amdgcn_mfma_f32_16x16x32_bf16(af[kt], bf, acc[nt], 0, 0, 0);
    }
  }

  // epilogue: relu(+bias) -> a1_s (bf16). Wave writes only its own 16 rows.
  #pragma unroll
  for (int nt = 0; nt < 8; ++nt) {
    const int n = nt * 16 + ln;
    const float bias = bias1[nt];
    #pragma unroll
    for (int r = 0; r < 4; ++r) {
      const int m = m0 + qd * 4 + r;
      a1_s[m * PH + n] = f2bf(fmaxf(acc[nt][r] + bias, 0.f));
    }
  }
  // no __syncthreads: each wave reads back only rows it wrote (DS in-order/wave)

  // ---- GEMM2: att[64m][16j] = a1[64m][128k] * w2e[16j][128k]^T
  f32x4 acc2 = f32x4{0.f, 0.f, 0.f, 0.f};
  #pragma unroll
  for (int kt = 0; kt < 4; ++kt) {
    const bf16x8 a2 = *(const bf16x8*)&a1_s[(m0 + ln) * PH + kt * 32 + qd * 8];
    acc2 = __builtin_amdgcn_mfma_f32_16x16x32_bf16(a2, b2f[kt], acc2, 0, 0, 0);
  }
  #pragma unroll
  for (int r = 0; r < 4; ++r) {
    const int opx = m0 + qd * 4 + r;
    const float v = fmaxf(acc2[r] + bias2, 0.f) + 0.001f;
    att[((size_t)((b * Hc + y) * Wc) + xg0 + opx) * NA + ln] = v;
  }
}

// ---------------------------------------------------------------------------
// K2: block = one image row (192 threads), thread = pixel.
// pb y-interpolated at stage time -> row_s[64][96] f32 (24 KB -> 6 blk/CU),
// delta with 4 bins in flight, register bitonic sort.
// ---------------------------------------------------------------------------
__global__ __launch_bounds__(192, 2) void k_bins(
    const float* __restrict__ pb, const float* __restrict__ att,
    float* __restrict__ out0, float* __restrict__ out1)
{
  __shared__ __align__(16) float row_s[NB][WI];   // 24576 B

  const int tid = threadIdx.x;      // = xg
  const int y = blockIdx.x;
  const int b = blockIdx.y;

  const float ysf = y * SCL;
  const int y0 = (int)ysf;
  const int y1 = min(y0 + 1, HI - 1);
  const float wy = ysf - (float)y0;

  // att for this pixel: 16 floats, contiguous — issue first (independent)
  float am[16];
  {
    const float4* ap = (const float4*)(att + ((size_t)((b * Hc + y) * Wc) + tid) * NA);
    const float4 a0 = ap[0], a1 = ap[1], a2 = ap[2], a3 = ap[3];
    am[0] = a0.x;  am[1] = a0.y;  am[2] = a0.z;  am[3] = a0.w;
    am[4] = a1.x;  am[5] = a1.y;  am[6] = a1.z;  am[7] = a1.w;
    am[8] = a2.x;  am[9] = a2.y;  am[10] = a2.z; am[11] = a2.w;
    am[12] = a3.x; am[13] = a3.y; am[14] = a3.z; am[15] = a3.w;
  }

  // ---- stage y-interpolated pb rows for all 64 bins: 1536 float4 positions
  #pragma unroll
  for (int i = 0; i < 8; ++i) {
    const int u = tid + 192 * i;          // 0..1535
    const int k = u / 24;
    const int g = u - k * 24;             // float4 group in row
    const float* base = pb + (size_t)(b * NB + k) * (HI * WI);
    const float4 t4 = *(const float4*)&base[y0 * WI + g * 4];
    const float4 b4 = *(const float4*)&base[y1 * WI + g * 4];
    float4 r;
    r.x = t4.x + wy * (b4.x - t4.x);
    r.y = t4.y + wy * (b4.y - t4.y);
    r.z = t4.z + wy * (b4.z - t4.z);
    r.w = t4.w + wy * (b4.w - t4.w);
    *(float4*)&row_s[k][g * 4] = r;
  }
  __syncthreads();

  const float xsf = tid * SCL;
  const int x0 = (int)xsf;          // <= 94
  const float wx = xsf - (float)x0;

  const size_t obase = (size_t)(b * NB) * (Hc * Wc) + (size_t)y * Wc + tid;
  float v[NB];

  // ---- delta: 4 bins in flight -> 4 independent rcp chains
  #pragma unroll
  for (int kb = 0; kb < NB; kb += 4) {
    float bc[4], dl[4];
    #pragma unroll
    for (int q = 0; q < 4; ++q) {
      const int k = kb + q;
      const float v0 = row_s[k][x0], v1 = row_s[k][x0 + 1];
      bc[q] = v0 + wx * (v1 - v0);
      dl[q] = 0.f;
    }
    #pragma unroll
    for (int j = 0; j < NA; ++j) {
      const float a = am[j];
      #pragma unroll
      for (int q = 0; q < 4; ++q) {
        const float d = a - bc[q];
        const float rq = fmaf(300.f * d, d, 1.f);
        dl[q] = fmaf(d, rcp_fast(rq), dl[q]);
      }
    }
    #pragma unroll
    for (int q = 0; q < 4; ++q) {
      const float bnc = fmaf(dl[q], 1.f / 16.f, bc[q]);
      out0[obase + (size_t)(kb + q) * (Hc * Wc)] = bnc;
      v[kb + q] = fmaf(9.999f, bnc, 0.001f);
    }
  }

  // ---- fully-unrolled bitonic sort on 64 registers (ascending)
  #pragma unroll
  for (int size = 2; size <= NB; size <<= 1) {
    #pragma unroll
    for (int stride = size >> 1; stride >= 1; stride >>= 1) {
      #pragma unroll
      for (int i = 0; i < NB; ++i) {
        if ((i & stride) == 0) {
          const int j = i | stride;
          const bool asc = ((i & size) == 0);
          const float a = v[i], c = v[j];
          const float lo = fminf(a, c), hi = fmaxf(a, c);
          v[i] = asc ? lo : hi;
          v[j] = asc ? hi : lo;
        }
      }
    }
  }

  #pragma unroll
  for (int k = 0; k < NB; ++k) {
    out1[obase + (size_t)k * (Hc * Wc)] = fminf(fmaxf(v[k], 0.001f), 10.0f);
  }
}

// ---------------------------------------------------------------------------
extern "C" void kernel_launch(void* const* d_in, const int* in_sizes, int n_in,
                              void* d_out, int out_size, void* d_ws, size_t ws_size,
                              hipStream_t stream) {
  const float* x   = (const float*)d_in[0];   // (4,128,192,192)
  const float* pb  = (const float*)d_in[1];   // (4,64,96,96)
  const float* pbe = (const float*)d_in[2];   // (4,128,96,96)
  const float* w1  = (const float*)d_in[3];   // (128,128)
  const float* b1  = (const float*)d_in[4];   // (128,)
  const float* w2  = (const float*)d_in[5];   // (32,128)
  const float* b2  = (const float*)d_in[6];   // (32,)

  float* out0 = (float*)d_out;                       // bin_new_centers
  float* out1 = out0 + (size_t)Bc * NB * Hc * Wc;    // bin_centers

  // ws layout: [w1p 32KB][w2p 4KB][pad to 64KB][att f32 9.4MB]
  unsigned short* w1p = (unsigned short*)d_ws;
  unsigned short* w2p = w1p + 16384;
  float* att = (float*)((char*)d_ws + 65536);        // [b][y][x][j]

  k_prep<<<72, 256, 0, stream>>>(w1, w2, w1p, w2p);

  dim3 g1(Wc / 64, Hc, Bc);
  k_att<<<g1, 256, 0, stream>>>(x, pbe, w1p, b1, w2p, b2, att);

  dim3 g2(Hc, Bc);
  k_bins<<<g2, 192, 0, stream>>>(pb, att, out0, out1);
}

// Round 3
// 212.960 us; speedup vs baseline: 1.2022x; 1.0201x over previous
//
#include <hip/hip_runtime.h>

// Problem dims (fixed by setup_inputs)
constexpr int Bc = 4, Cc = 128, Hc = 192, Wc = 192;
constexpr int HI = 96, WI = 96;       // half-res inputs
constexpr int NB = 64;                // n_bins
constexpr int NA = 16;                // n_att
constexpr float SCL = 95.0f / 191.0f; // align_corners scale (96->192)

typedef __attribute__((ext_vector_type(8))) short bf16x8;
typedef __attribute__((ext_vector_type(4))) float f32x4;

__device__ __forceinline__ unsigned short f2bf(float f) {
  unsigned u = __builtin_bit_cast(unsigned, f);
  unsigned r = (u + 0x7FFFu + ((u >> 16) & 1u)) >> 16;   // RNE
  return (unsigned short)r;
}
__device__ __forceinline__ float rcp_fast(float r) {
#if defined(__has_builtin)
#if __has_builtin(__builtin_amdgcn_rcpf)
  return __builtin_amdgcn_rcpf(r);
#else
  return 1.0f / r;
#endif
#else
  return 1.0f / r;
#endif
}

// ---------------------------------------------------------------------------
// Prep: pack w1 / even rows of w2 into MFMA-fragment order (bf16):
//   w1p[(nt*4+kt)*512 + l*8 + e] = w1[(nt*16 + (l&15))*128 + kt*32 + (l>>4)*8 + e]
//   w2p[kt*512 + l*8 + e]        = w2[(2*(l&15))*128   + kt*32 + (l>>4)*8 + e]
// ---------------------------------------------------------------------------
__global__ __launch_bounds__(256) void k_prep(
    const float* __restrict__ w1, const float* __restrict__ w2,
    unsigned short* __restrict__ w1p, unsigned short* __restrict__ w2p)
{
  const int t = blockIdx.x * 256 + threadIdx.x;   // 0..18431
  if (t < 16384) {
    const int e  = t & 7;
    const int l  = (t >> 3) & 63;
    const int kt = (t >> 9) & 3;
    const int nt = t >> 11;
    const int n  = nt * 16 + (l & 15);
    const int k  = kt * 32 + (l >> 4) * 8 + e;
    w1p[t] = f2bf(w1[n * 128 + k]);
  } else {
    const int u  = t - 16384;                     // 0..2047
    const int e  = u & 7;
    const int l  = (u >> 3) & 63;
    const int kt = u >> 9;
    const int n  = 2 * (l & 15);                  // even rows only
    const int k  = kt * 32 + (l >> 4) * 8 + e;
    w2p[u] = f2bf(w2[n * 128 + k]);
  }
}

// ---------------------------------------------------------------------------
// K1 (MFMA): h = x + bilinear(pbe); a1 = relu(h@w1^T+b1);
//            att = relu(a1@w2e^T+b2e)+1e-3  -> att_ws[b][y][x][j]
// One block per (b, y, 64-px x-tile). 256 threads = 4 waves.
// R2 (kept): w1 pre-packed in fragment order, staged to LDS once per block;
// GEMM1 B-reads are conflict-free ds_read_b128. LDS 51.7KB -> 3 blocks/CU.
// R1 lesson: (256,8) crushed VGPRs to 32 and regressed; keep (256,3).
// ---------------------------------------------------------------------------
__global__ __launch_bounds__(256, 3) void k_att(
    const float* __restrict__ x, const float* __restrict__ pbe,
    const unsigned short* __restrict__ w1p, const float* __restrict__ b1,
    const unsigned short* __restrict__ w2p, const float* __restrict__ b2,
    float* __restrict__ att)
{
  constexpr int PH = 136;   // a1_s pitch (bf16)
  constexpr int RP = 37;    // row_s pitch (f32), odd
  __shared__ __align__(16) unsigned char smem[32768 + 128 * RP * 4];
  unsigned short* w1_s  = (unsigned short*)smem;                // frag-linear
  float*          row_s = (float*)(smem + 32768);               // [128][37]
  unsigned short* a1_s  = (unsigned short*)(smem + 32768);      // [64][136]

  const int tid = threadIdx.x;
  const int xg0 = blockIdx.x * 64;
  const int y = blockIdx.y;
  const int b = blockIdx.z;

  const float ysf = y * SCL;
  const int y0 = (int)ysf;
  const int y1 = min(y0 + 1, HI - 1);
  const float wy = ysf - (float)y0;
  const int xi0 = (int)(xg0 * SCL);

  const int lane = tid & 63;
  const int wv = tid >> 6;        // wave id 0..3
  const int ln = lane & 15;
  const int qd = lane >> 4;
  const int m0 = wv * 16;

  const int px = m0 + ln;
  const int xg = xg0 + px;
  const float xsf = (float)xg * SCL;
  const int x0i = (int)xsf;
  const float wx = xsf - (float)x0i;
  const int xl = x0i - xi0;             // 0..32, xl+1 <= 33

  // ---- w1p stage loads (global->reg), issued first: 8 x float4 per thread
  float4 wstage[8];
  {
    const float4* wp4 = (const float4*)w1p;   // 2048 float4
    #pragma unroll
    for (int i = 0; i < 8; ++i) wstage[i] = wp4[tid + 256 * i];
  }

  // ---- hoisted w2 fragments (4 x 16B, L2-hot) + biases
  bf16x8 b2f[4];
  #pragma unroll
  for (int kt = 0; kt < 4; ++kt)
    b2f[kt] = *(const bf16x8*)&w2p[kt * 512 + lane * 8];
  float bias1[8];
  #pragma unroll
  for (int nt = 0; nt < 8; ++nt) bias1[nt] = b1[nt * 16 + ln];
  const float bias2 = b2[2 * ln];

  // ---- hoisted x loads: xr[kt*8+j] = x[c = kt*32+qd*8+j][y][xg]
  float xr[32];
  #pragma unroll
  for (int kt = 0; kt < 4; ++kt) {
    #pragma unroll
    for (int j = 0; j < 8; ++j) {
      const int c = kt * 32 + qd * 8 + j;
      xr[kt * 8 + j] = x[((size_t)(b * Cc + c) * Hc + y) * Wc + xg];
    }
  }

  // ---- phase 1: row_s[c][xi] = y-interp of pbe (coalesced loads, f32)
  #pragma unroll
  for (int i = 0; i < 18; ++i) {
    const int f = tid + 256 * i;        // 0..4607
    const int c = f / 36;
    const int xi = f - c * 36;
    const int xgl = min(xi0 + xi, WI - 1);
    const float* p = pbe + (size_t)(b * Cc + c) * (HI * WI);
    const float top = p[y0 * WI + xgl];
    const float bot = p[y1 * WI + xgl];
    row_s[c * RP + xi] = top + wy * (bot - top);
  }

  // ---- w1 stage: reg -> LDS (linear, conflict-free)
  {
    float4* ws4 = (float4*)w1_s;
    #pragma unroll
    for (int i = 0; i < 8; ++i) ws4[tid + 256 * i] = wstage[i];
  }
  __syncthreads();

  // ---- build A-fragments in registers from xr + row_s
  bf16x8 af[4];
  #pragma unroll
  for (int kt = 0; kt < 4; ++kt) {
    #pragma unroll
    for (int j = 0; j < 8; ++j) {
      const int c = kt * 32 + qd * 8 + j;
      const float v0 = row_s[c * RP + xl];
      const float v1 = row_s[c * RP + xl + 1];
      af[kt][j] = (short)f2bf(xr[kt * 8 + j] + v0 + wx * (v1 - v0));
    }
  }
  __syncthreads();   // row_s dead -> region reusable as a1_s

  // ---- GEMM1: C[64m][128n] = h[64m][128k] * w1[128n][128k]^T (B from LDS)
  f32x4 acc[8];
  #pragma unroll
  for (int nt = 0; nt < 8; ++nt) acc[nt] = f32x4{0.f, 0.f, 0.f, 0.f};
  #pragma unroll
  for (int nt = 0; nt < 8; ++nt) {
    #pragma unroll
    for (int kt = 0; kt < 4; ++kt) {
      const bf16x8 bf = *(const bf16x8*)&w1_s[(nt * 4 + kt) * 512 + lane * 8];
      acc[nt] = __builtin_amdgcn_mfma_f32_16x16x32_bf16(af[kt], bf, acc[nt], 0, 0, 0);
    }
  }

  // epilogue: relu(+bias) -> a1_s (bf16). Wave writes only its own 16 rows.
  #pragma unroll
  for (int nt = 0; nt < 8; ++nt) {
    const int n = nt * 16 + ln;
    const float bias = bias1[nt];
    #pragma unroll
    for (int r = 0; r < 4; ++r) {
      const int m = m0 + qd * 4 + r;
      a1_s[m * PH + n] = f2bf(fmaxf(acc[nt][r] + bias, 0.f));
    }
  }
  // no __syncthreads: each wave reads back only rows it wrote

  // ---- GEMM2: att[64m][16j] = a1[64m][128k] * w2e[16j][128k]^T
  f32x4 acc2 = f32x4{0.f, 0.f, 0.f, 0.f};
  #pragma unroll
  for (int kt = 0; kt < 4; ++kt) {
    const bf16x8 a2 = *(const bf16x8*)&a1_s[(m0 + ln) * PH + kt * 32 + qd * 8];
    acc2 = __builtin_amdgcn_mfma_f32_16x16x32_bf16(a2, b2f[kt], acc2, 0, 0, 0);
  }
  #pragma unroll
  for (int r = 0; r < 4; ++r) {
    const int opx = m0 + qd * 4 + r;
    const float v = fmaxf(acc2[r] + bias2, 0.f) + 0.001f;
    att[((size_t)((b * Hc + y) * Wc) + xg0 + opx) * NA + ln] = v;
  }
}

// ---------------------------------------------------------------------------
// K2: block = one image row, 384 threads = 192 px x 2 bin-halves.
// R3: old k_bins was latency-bound (Occ 25%: grid 768 x 3 waves = 9 waves/CU;
// 1024 rcp + 672-CE bitonic-64 per thread; v[64]+am[16] > 76 VGPR).
// Split bins across 2 threads/pixel: 18 waves/CU, 512 rcp, sort-32 + one
// cross-thread bitonic merge layer through LDS (aliases dead row_s).
// h is wave-uniform (waves 0-2 = h0, 3-5 = h1) -> no divergence.
// ---------------------------------------------------------------------------
__global__ __launch_bounds__(384, 4) void k_bins(
    const float* __restrict__ pb, const float* __restrict__ att,
    float* __restrict__ out0, float* __restrict__ out1)
{
  __shared__ __align__(16) float row_s[NB][WI];   // 24576 B; aliased as xch
  float* xch = &row_s[0][0];                      // [32][192] after delta

  const int tid = threadIdx.x;      // 0..383
  const int h = (tid >= 192) ? 1 : 0;   // bin half (wave-uniform)
  const int px = tid - 192 * h;         // pixel 0..191
  const int y = blockIdx.x;
  const int b = blockIdx.y;

  const float ysf = y * SCL;
  const int y0 = (int)ysf;
  const int y1 = min(y0 + 1, HI - 1);
  const float wy = ysf - (float)y0;

  // att for this pixel: 16 floats, contiguous — issue first (independent)
  float am[16];
  {
    const float4* ap = (const float4*)(att + ((size_t)((b * Hc + y) * Wc) + px) * NA);
    const float4 a0 = ap[0], a1 = ap[1], a2 = ap[2], a3 = ap[3];
    am[0] = a0.x;  am[1] = a0.y;  am[2] = a0.z;  am[3] = a0.w;
    am[4] = a1.x;  am[5] = a1.y;  am[6] = a1.z;  am[7] = a1.w;
    am[8] = a2.x;  am[9] = a2.y;  am[10] = a2.z; am[11] = a2.w;
    am[12] = a3.x; am[13] = a3.y; am[14] = a3.z; am[15] = a3.w;
  }

  // ---- stage y-interpolated pb rows for all 64 bins: 1536 float4 positions
  #pragma unroll
  for (int i = 0; i < 4; ++i) {
    const int u = tid + 384 * i;          // 0..1535
    const int k = u / 24;
    const int g = u - k * 24;             // float4 group in row
    const float* base = pb + (size_t)(b * NB + k) * (HI * WI);
    const float4 t4 = *(const float4*)&base[y0 * WI + g * 4];
    const float4 b4 = *(const float4*)&base[y1 * WI + g * 4];
    float4 r;
    r.x = t4.x + wy * (b4.x - t4.x);
    r.y = t4.y + wy * (b4.y - t4.y);
    r.z = t4.z + wy * (b4.z - t4.z);
    r.w = t4.w + wy * (b4.w - t4.w);
    *(float4*)&row_s[k][g * 4] = r;
  }
  __syncthreads();

  const float xsf = px * SCL;
  const int x0 = (int)xsf;          // <= 94
  const float wx = xsf - (float)x0;

  const size_t obase = (size_t)(b * NB) * (Hc * Wc) + (size_t)y * Wc + px;
  float v[32];                      // this thread's 32 bins (k = h*32 + i)

  // ---- delta: 4 bins in flight -> 4 independent rcp chains
  #pragma unroll
  for (int kb = 0; kb < 32; kb += 4) {
    float bc[4], dl[4];
    #pragma unroll
    for (int q = 0; q < 4; ++q) {
      const int k = h * 32 + kb + q;
      const float v0 = row_s[k][x0], v1 = row_s[k][x0 + 1];
      bc[q] = v0 + wx * (v1 - v0);
      dl[q] = 0.f;
    }
    #pragma unroll
    for (int j = 0; j < NA; ++j) {
      const float a = am[j];
      #pragma unroll
      for (int q = 0; q < 4; ++q) {
        const float d = a - bc[q];
        const float rq = fmaf(300.f * d, d, 1.f);
        dl[q] = fmaf(d, rcp_fast(rq), dl[q]);
      }
    }
    #pragma unroll
    for (int q = 0; q < 4; ++q) {
      const float bnc = fmaf(dl[q], 1.f / 16.f, bc[q]);
      out0[obase + (size_t)(h * 32 + kb + q) * (Hc * Wc)] = bnc;
      v[kb + q] = fmaf(9.999f, bnc, 0.001f);
    }
  }

  // ---- per-thread bitonic sort of 32: h0 ascending, h1 descending.
  // [h0 asc | h1 desc] forms a bitonic 64-sequence.
  if (h == 0) {
    #pragma unroll
    for (int size = 2; size <= 32; size <<= 1)
      #pragma unroll
      for (int stride = size >> 1; stride >= 1; stride >>= 1)
        #pragma unroll
        for (int i = 0; i < 32; ++i)
          if ((i & stride) == 0) {
            const int j = i | stride;
            const bool asc = ((i & size) == 0);
            const float a = v[i], c = v[j];
            const float lo = fminf(a, c), hi = fmaxf(a, c);
            v[i] = asc ? lo : hi;
            v[j] = asc ? hi : lo;
          }
  } else {
    #pragma unroll
    for (int size = 2; size <= 32; size <<= 1)
      #pragma unroll
      for (int stride = size >> 1; stride >= 1; stride >>= 1)
        #pragma unroll
        for (int i = 0; i < 32; ++i)
          if ((i & stride) == 0) {
            const int j = i | stride;
            const bool asc = ((i & size) != 0);   // descending overall
            const float a = v[i], c = v[j];
            const float lo = fminf(a, c), hi = fmaxf(a, c);
            v[i] = asc ? lo : hi;
            v[j] = asc ? hi : lo;
          }
  }

  // ---- cross-thread stride-32 CE layer through LDS (row_s is dead)
  __syncthreads();                       // all row_s reads done
  if (h) {
    #pragma unroll
    for (int i = 0; i < 32; ++i) xch[i * 192 + px] = v[i];
  }
  __syncthreads();
  if (!h) {
    #pragma unroll
    for (int i = 0; i < 32; ++i) {
      const float o = xch[i * 192 + px];
      const float mn = fminf(v[i], o), mx = fmaxf(v[i], o);
      v[i] = mn;
      xch[i * 192 + px] = mx;
    }
  }
  __syncthreads();
  if (h) {
    #pragma unroll
    for (int i = 0; i < 32; ++i) v[i] = xch[i * 192 + px];
  }

  // ---- each half is bitonic; 5 ascending merge layers finish the sort
  #pragma unroll
  for (int stride = 16; stride >= 1; stride >>= 1)
    #pragma unroll
    for (int i = 0; i < 32; ++i)
      if ((i & stride) == 0) {
        const int j = i | stride;
        const float a = v[i], c = v[j];
        v[i] = fminf(a, c);
        v[j] = fmaxf(a, c);
      }

  // h0 holds global ranks 0..31, h1 ranks 32..63
  #pragma unroll
  for (int i = 0; i < 32; ++i) {
    out1[obase + (size_t)(h * 32 + i) * (Hc * Wc)] =
        fminf(fmaxf(v[i], 0.001f), 10.0f);
  }
}

// ---------------------------------------------------------------------------
extern "C" void kernel_launch(void* const* d_in, const int* in_sizes, int n_in,
                              void* d_out, int out_size, void* d_ws, size_t ws_size,
                              hipStream_t stream) {
  const float* x   = (const float*)d_in[0];   // (4,128,192,192)
  const float* pb  = (const float*)d_in[1];   // (4,64,96,96)
  const float* pbe = (const float*)d_in[2];   // (4,128,96,96)
  const float* w1  = (const float*)d_in[3];   // (128,128)
  const float* b1  = (const float*)d_in[4];   // (128,)
  const float* w2  = (const float*)d_in[5];   // (32,128)
  const float* b2  = (const float*)d_in[6];   // (32,)

  float* out0 = (float*)d_out;                       // bin_new_centers
  float* out1 = out0 + (size_t)Bc * NB * Hc * Wc;    // bin_centers

  // ws layout: [w1p 32KB][w2p 4KB][pad to 64KB][att f32 9.4MB]
  unsigned short* w1p = (unsigned short*)d_ws;
  unsigned short* w2p = w1p + 16384;
  float* att = (float*)((char*)d_ws + 65536);        // [b][y][x][j]

  k_prep<<<72, 256, 0, stream>>>(w1, w2, w1p, w2p);

  dim3 g1(Wc / 64, Hc, Bc);
  k_att<<<g1, 256, 0, stream>>>(x, pbe, w1p, b1, w2p, b2, att);

  dim3 g2(Hc, Bc);
  k_bins<<<g2, 384, 0, stream>>>(pb, att, out0, out1);
}